// Round 6
// baseline (300.198 us; speedup 1.0000x reference)
//
#include <hip/hip_runtime.h>
#include <math.h>

#define BB 16
#define CC 128
#define HH 128
#define WW 128
#define LL 4096

typedef short short8 __attribute__((ext_vector_type(8)));
typedef float f32x4 __attribute__((ext_vector_type(4)));

__device__ __forceinline__ ushort f2bf(float f) {
    union { float f; unsigned u; } un; un.f = f;
    unsigned u = un.u;
    u += 0x7fffu + ((u >> 16) & 1u);   // RNE
    return (ushort)(u >> 16);
}
__device__ __forceinline__ float bf2f(ushort h) {
    union { unsigned u; float f; } un; un.u = ((unsigned)h) << 16;
    return un.f;
}
// tanh-form GELU via sigmoid
__device__ __forceinline__ float fast_gelu(float xv) {
    float x2 = xv*xv;
    float arg = xv*(-2.3022100f - 0.1029436f*x2);
    float e = exp2f(arg);
    return xv*__builtin_amdgcn_rcpf(1.f + e);
}

// ---- prep: Wq/Wk -> bf16; cvec = proj@bv + proj_b ----
__global__ __launch_bounds__(256) void prep_small(
    const float* __restrict__ qkv_w, const float* __restrict__ qkv_b,
    const float* __restrict__ proj_w, const float* __restrict__ proj_b,
    ushort* __restrict__ wqk, float* __restrict__ cvec)
{
    int t = threadIdx.x;
    int gid = blockIdx.x*256 + t;
    wqk[gid] = f2bf(qkv_w[gid]);
    if (blockIdx.x == 1 && t < CC) {
        float s = proj_b[t];
        const float* pr = proj_w + t*CC;
        const float* bv = qkv_b + 2*CC;
        for (int c = 0; c < CC; ++c) s += pr[c]*bv[c];
        cvec[t] = s;
    }
}

// ---- guide = dwconv7x7_s2(gelu(bn(x))), bf16 out [b][c][64*64] ----
// 4 outputs/thread along w; conv reads = 28 ds_read_b128/thread; weights in SGPRs.
__global__ __launch_bounds__(256) void guide_kernel(
    const float* __restrict__ x, const float* __restrict__ gamma,
    const float* __restrict__ beta, const float* __restrict__ mean,
    const float* __restrict__ var, const float* __restrict__ dww,
    const float* __restrict__ dwb, ushort* __restrict__ gw)
{
    int bc = blockIdx.x;
    int b = bc >> 7, c = bc & 127;
    int ty = blockIdx.y, th0 = ty << 4;      // 16 output rows x 64 cols
    __shared__ float g[38][136];
    int t = threadIdx.x;
    // uniform weight preload (scalar loads, no LDS)
    float wreg[49];
    #pragma unroll
    for (int k = 0; k < 49; ++k) wreg[k] = dww[c*49 + k];
    float bias = dwb[c];
    float scl = gamma[c] * rsqrtf(var[c] + 1e-5f);
    float sft = beta[c] - mean[c]*scl;
    const float* xb = x + (size_t)(b*CC + c)*HH*WW;
    int ih0 = 2*th0 - 3;
    for (int idx = t; idx < 38*134; idx += 256) {
        int rr = idx/134, q = idx - rr*134;
        int ih = ih0 + rr, iw = q - 3;
        float v = 0.f;
        if ((unsigned)ih < (unsigned)HH && (unsigned)iw < (unsigned)WW) {
            float xv = xb[ih*WW + iw];
            v = fast_gelu(xv*scl + sft);
        }
        g[rr][q] = v;
    }
    __syncthreads();
    int ol = t >> 4, owg = t & 15;           // output row, w-group of 4
    float acc0 = bias, acc1 = bias, acc2 = bias, acc3 = bias;
    #pragma unroll
    for (int kh = 0; kh < 7; ++kh) {
        const float4* rp = (const float4*)&g[2*ol + kh][owg*8];
        float4 r0 = rp[0], r1 = rp[1], r2 = rp[2], r3 = rp[3];
        float win[16] = {r0.x,r0.y,r0.z,r0.w, r1.x,r1.y,r1.z,r1.w,
                         r2.x,r2.y,r2.z,r2.w, r3.x,r3.y,r3.z,r3.w};
        #pragma unroll
        for (int kw = 0; kw < 7; ++kw) {
            float wv = wreg[kh*7 + kw];
            acc0 += wv * win[kw];
            acc1 += wv * win[2 + kw];
            acc2 += wv * win[4 + kw];
            acc3 += wv * win[6 + kw];
        }
    }
    ushort o0 = f2bf(acc0), o1 = f2bf(acc1), o2 = f2bf(acc2), o3 = f2bf(acc3);
    uint2 pk;
    pk.x = (unsigned)o0 | ((unsigned)o1 << 16);
    pk.y = (unsigned)o2 | ((unsigned)o3 << 16);
    *(uint2*)(gw + ((size_t)(b*CC + c) << 12) + (th0 + ol)*64 + owg*4) = pk;
}

// ---- stage 5 tokens (bf16) for one 32-l chunk into LDS [m][l][c] pad+8, coalesced ----
__device__ __forceinline__ void stage_tok2(
    ushort* tok, const float* __restrict__ x, const ushort* __restrict__ gw,
    int b, int h, int whalf, int t)
{
    int c = t >> 1, r = t & 1;
    const float* xrow = x + ((size_t)(b*CC + c)*HH + (2*h + r))*WW + whalf*64;
    int m0 = (1 + 2*r)*32, m1 = (2 + 2*r)*32;
    #pragma unroll
    for (int i = 0; i < 16; ++i) {
        float4 v = ((const float4*)xrow)[i];
        tok[(m0 + 2*i    )*136 + c] = f2bf(v.x);
        tok[(m1 + 2*i    )*136 + c] = f2bf(v.y);
        tok[(m0 + 2*i + 1)*136 + c] = f2bf(v.z);
        tok[(m1 + 2*i + 1)*136 + c] = f2bf(v.w);
    }
    const ushort* gsrc = gw + ((size_t)(b*CC + c) << 12) + h*64 + whalf*32 + r*16;
    uint4 g0 = *(const uint4*)gsrc;
    uint4 g1 = *(const uint4*)(gsrc + 8);
    unsigned wd[8] = {g0.x,g0.y,g0.z,g0.w,g1.x,g1.y,g1.z,g1.w};
    #pragma unroll
    for (int k2 = 0; k2 < 8; ++k2) {
        tok[(r*16 + 2*k2    )*136 + c] = (ushort)wd[k2];
        tok[(r*16 + 2*k2 + 1)*136 + c] = (ushort)(wd[k2] >> 16);
    }
}

// ---- phase A: per-block partial S (640) + token-sum partial T (640), 2 chunks/block ----
__global__ __launch_bounds__(256) void s_kernel(
    const float* __restrict__ x, const ushort* __restrict__ gw,
    const ushort* __restrict__ wqk, float* __restrict__ Spart)
{
    __shared__ __align__(16) ushort tok[5*32*136];
    __shared__ float Sred[640];
    int t = threadIdx.x;
    int blk = blockIdx.x;
    int b = blk >> 6, pair = blk & 63;
    int lane = t & 63, wave = t >> 6;
    int strip = wave*32;
    short8 aq[2][4], ak[2][4];
    #pragma unroll
    for (int mt = 0; mt < 2; ++mt)
        #pragma unroll
        for (int kt = 0; kt < 4; ++kt) {
            int off = (strip + mt*16 + (lane & 15))*CC + kt*32 + (lane >> 4)*8;
            aq[mt][kt] = *(const short8*)(wqk + off);
            ak[mt][kt] = *(const short8*)(wqk + CC*CC + off);
        }
    float sacc[5][8];
    #pragma unroll
    for (int m = 0; m < 5; ++m)
        #pragma unroll
        for (int i = 0; i < 8; ++i) sacc[m][i] = 0.f;
    float tacc[3] = {0.f, 0.f, 0.f};
    const ushort* tb = tok + (lane & 15)*136 + (lane >> 4)*8;

    #pragma unroll
    for (int cidx = 0; cidx < 2; ++cidx) {
        int chunk = pair*2 + cidx;
        int h = chunk >> 1, whalf = chunk & 1;
        if (cidx) __syncthreads();
        stage_tok2(tok, x, gw, b, h, whalf, t);
        __syncthreads();
        #pragma unroll
        for (int j = 0; j < 3; ++j) {
            int i = t + j*256;
            if (i < 640) {
                int m = i >> 7, cch = i & 127;
                float s = 0.f;
                for (int l = 0; l < 32; ++l) s += bf2f(tok[(m*32 + l)*136 + cch]);
                tacc[j] += s;
            }
        }
        f32x4 q0[2][2] = {};
        #pragma unroll
        for (int kt = 0; kt < 4; ++kt)
            #pragma unroll
            for (int nt = 0; nt < 2; ++nt) {
                short8 bf = *(const short8*)(tb + (nt*16)*136 + kt*32);
                #pragma unroll
                for (int mt = 0; mt < 2; ++mt)
                    q0[mt][nt] = __builtin_amdgcn_mfma_f32_16x16x32_bf16(aq[mt][kt], bf, q0[mt][nt], 0, 0, 0);
            }
        #pragma unroll
        for (int m = 0; m < 5; ++m) {
            f32x4 ka[2][2] = {};
            #pragma unroll
            for (int kt = 0; kt < 4; ++kt)
                #pragma unroll
                for (int nt = 0; nt < 2; ++nt) {
                    short8 bf = *(const short8*)(tb + (m*32 + nt*16)*136 + kt*32);
                    #pragma unroll
                    for (int mt = 0; mt < 2; ++mt)
                        ka[mt][nt] = __builtin_amdgcn_mfma_f32_16x16x32_bf16(ak[mt][kt], bf, ka[mt][nt], 0, 0, 0);
                }
            #pragma unroll
            for (int mt = 0; mt < 2; ++mt)
                #pragma unroll
                for (int nt = 0; nt < 2; ++nt)
                    #pragma unroll
                    for (int rr = 0; rr < 4; ++rr)
                        sacc[m][mt*4 + rr] += q0[mt][nt][rr]*ka[mt][nt][rr];
        }
    }
    #pragma unroll
    for (int m = 0; m < 5; ++m)
        #pragma unroll
        for (int i = 0; i < 8; ++i) {
            float v = sacc[m][i];
            v += __shfl_xor(v, 1); v += __shfl_xor(v, 2);
            v += __shfl_xor(v, 4); v += __shfl_xor(v, 8);
            if ((lane & 15) == 0)
                Sred[(strip + (i >> 2)*16 + (lane >> 4)*4 + (i & 3))*5 + m] = v;
        }
    __syncthreads();
    float* Sp = Spart + (size_t)blk*1280;
    for (int i = t; i < 640; i += 256) Sp[i] = Sred[i];
    #pragma unroll
    for (int j = 0; j < 3; ++j) {
        int i = t + j*256;
        if (i < 640) Sp[640 + i] = tacc[j];
    }
}

// ---- reduce partials + exact bias + softmax ----
__global__ __launch_bounds__(256) void softmax_attn(
    const float* __restrict__ Spart,
    const float* __restrict__ qkv_w, const float* __restrict__ qkv_b,
    float* __restrict__ attn)
{
    __shared__ float TsumL[640];   // [m][c]
    __shared__ float SL[640];      // [c][m]
    int b = blockIdx.x, t = threadIdx.x;
    for (int i = t; i < 640; i += 256) {
        float s2 = 0.f, ts = 0.f;
        for (int p = 0; p < 64; ++p) {
            const float* row = Spart + (size_t)(b*64 + p)*1280;
            s2 += row[i];
            ts += row[640 + i];
        }
        SL[i] = s2;
        TsumL[i] = ts;
    }
    __syncthreads();
    if (t < CC) {
        int c = t;
        float bq = qkv_b[c], bk = qkv_b[CC + c];
        const float* wqr = qkv_w + c*CC;
        const float* wkr = qkv_w + (CC + c)*CC;
        float t0dot = 0.f;
        for (int j = 0; j < CC; ++j) t0dot += wqr[j]*TsumL[j];
        float s[5];
        #pragma unroll
        for (int m = 0; m < 5; ++m) {
            float km = 0.f;
            for (int j = 0; j < CC; ++j) km += wkr[j]*TsumL[m*128 + j];
            s[m] = SL[c*5 + m] + bq*km + bk*t0dot + (float)LL*bq*bk;
        }
        const float scale = 0.08838834764831845f;  // 1/sqrt(128)
        float mx = s[0]*scale;
        #pragma unroll
        for (int m = 1; m < 5; ++m) mx = fmaxf(mx, s[m]*scale);
        float e[5], tot = 0.f;
        #pragma unroll
        for (int m = 0; m < 5; ++m) { e[m] = expf(s[m]*scale - mx); tot += e[m]; }
        float inv = 1.f/tot;
        #pragma unroll
        for (int m = 0; m < 5; ++m) attn[(b*CC + c)*5 + m] = e[m]*inv;
    }
}

// ---- PW_m[b] = (proj .* attn_m) @ Wv, bf16 [b][m][c_out][c_in] ----
__global__ __launch_bounds__(256) void pw_kernel(
    const float* __restrict__ qkv_w, const float* __restrict__ proj_w,
    const float* __restrict__ attn, ushort* __restrict__ PW)
{
    __shared__ float attns[CC];
    __shared__ float wvs[32*CC];
    int blk = blockIdx.x;
    int b = blk / 5, m = blk % 5;
    int t = threadIdx.x;
    if (t < CC) attns[t] = attn[(b*CC + t)*5 + m];
    int d = t >> 1, cb = (t & 1)*64;
    float acc[64];
    #pragma unroll
    for (int j = 0; j < 64; ++j) acc[j] = 0.f;
    for (int cc0 = 0; cc0 < CC; cc0 += 32) {
        __syncthreads();
        for (int idx = t; idx < 32*CC; idx += 256) {
            int row = idx >> 7, col = idx & 127;
            wvs[idx] = qkv_w[(2*CC + cc0 + row)*CC + col];
        }
        __syncthreads();
        for (int cl = 0; cl < 32; ++cl) {
            int c = cc0 + cl;
            float a = proj_w[d*CC + c]*attns[c];
            const float* wr = wvs + cl*CC + cb;
            #pragma unroll
            for (int j = 0; j < 64; ++j) acc[j] += a*wr[j];
        }
    }
    ushort* dst = PW + ((size_t)(b*5 + m) << 14) + d*CC + cb;
    #pragma unroll
    for (int j = 0; j < 64; ++j) dst[j] = f2bf(acc[j]);
}

// ---- phase B: Y[l][c_out] = sum_{m,c} tok[m][l][c] * PW_m[c_out][c] + cvec ----
__global__ __launch_bounds__(256) void y_kernel(
    const float* __restrict__ x, const ushort* __restrict__ gw,
    const ushort* __restrict__ PW, const float* __restrict__ cvec,
    float* __restrict__ out)
{
    __shared__ __align__(16) ushort tok[5*32*136];   // reused as ylds[128][36] f32
    int t = threadIdx.x;
    int b = blockIdx.x >> 7, chunk = blockIdx.x & 127;
    int h = chunk >> 1, whalf = chunk & 1;
    stage_tok2(tok, x, gw, b, h, whalf, t);
    __syncthreads();
    int lane = t & 63, wave = t >> 6;
    const ushort* ta = tok + (lane & 15)*136 + (lane >> 4)*8;  // A: row=l, k=c
    f32x4 acc[2][2] = {};
    #pragma unroll
    for (int m = 0; m < 5; ++m) {
        const ushort* pwb = PW + ((size_t)(b*5 + m) << 14)
                          + ((wave*32 + (lane & 15)) << 7) + ((lane >> 4) << 3);
        #pragma unroll
        for (int kt = 0; kt < 4; ++kt) {
            short8 a0 = *(const short8*)(ta + (m*32     )*136 + kt*32);
            short8 a1 = *(const short8*)(ta + (m*32 + 16)*136 + kt*32);
            short8 b0 = *(const short8*)(pwb + kt*32);
            short8 b1 = *(const short8*)(pwb + (16 << 7) + kt*32);
            acc[0][0] = __builtin_amdgcn_mfma_f32_16x16x32_bf16(a0, b0, acc[0][0], 0, 0, 0);
            acc[0][1] = __builtin_amdgcn_mfma_f32_16x16x32_bf16(a0, b1, acc[0][1], 0, 0, 0);
            acc[1][0] = __builtin_amdgcn_mfma_f32_16x16x32_bf16(a1, b0, acc[1][0], 0, 0, 0);
            acc[1][1] = __builtin_amdgcn_mfma_f32_16x16x32_bf16(a1, b1, acc[1][1], 0, 0, 0);
        }
    }
    __syncthreads();
    float* ylds = (float*)tok;   // [128][36]
    #pragma unroll
    for (int mt = 0; mt < 2; ++mt)
        #pragma unroll
        for (int ntl = 0; ntl < 2; ++ntl) {
            int cc = wave*32 + ntl*16 + (lane & 15);
            float cv = cvec[cc];
            #pragma unroll
            for (int rr = 0; rr < 4; ++rr) {
                int l = mt*16 + (lane >> 4)*4 + rr;
                ylds[cc*36 + l] = acc[mt][ntl][rr] + cv;
            }
        }
    __syncthreads();
    int c = t >> 1, half = t & 1;
    float* ob = out + ((size_t)(b*CC + c) << 12) + h*64 + whalf*32 + half*16;
    const float* yr = ylds + c*36 + half*16;
    #pragma unroll
    for (int j = 0; j < 4; ++j)
        ((float4*)ob)[j] = ((const float4*)yr)[j];
}

extern "C" void kernel_launch(void* const* d_in, const int* in_sizes, int n_in,
                              void* d_out, int out_size, void* d_ws, size_t ws_size,
                              hipStream_t stream) {
    const float* x        = (const float*)d_in[0];
    const float* bn_gamma = (const float*)d_in[1];
    const float* bn_beta  = (const float*)d_in[2];
    const float* bn_mean  = (const float*)d_in[3];
    const float* bn_var   = (const float*)d_in[4];
    const float* dw_w     = (const float*)d_in[5];
    const float* dw_b     = (const float*)d_in[6];
    const float* qkv_w    = (const float*)d_in[7];
    const float* qkv_b    = (const float*)d_in[8];
    const float* proj_w   = (const float*)d_in[9];
    const float* proj_b   = (const float*)d_in[10];
    float* out = (float*)d_out;

    char* w = (char*)d_ws;
    ushort* gw    = (ushort*)w; w += (size_t)BB*CC*LL*2;        // 16 MB
    ushort* wqk   = (ushort*)w; w += (size_t)2*CC*CC*2;         // 64 KB
    ushort* PW    = (ushort*)w; w += (size_t)BB*5*CC*CC*2;      // 2.5 MB
    float*  Spart = (float*)w;  w += (size_t)1024*1280*4;       // 5.24 MB
    float*  attn  = (float*)w;  w += (size_t)BB*CC*5*4;         // 40 KB
    float*  cvec  = (float*)w;  w += (size_t)CC*4;

    prep_small<<<128, 256, 0, stream>>>(qkv_w, qkv_b, proj_w, proj_b, wqk, cvec);
    guide_kernel<<<dim3(BB*CC, 4), 256, 0, stream>>>(
        x, bn_gamma, bn_beta, bn_mean, bn_var, dw_w, dw_b, gw);
    s_kernel<<<1024, 256, 0, stream>>>(x, gw, wqk, Spart);
    softmax_attn<<<BB, 256, 0, stream>>>(Spart, qkv_w, qkv_b, attn);
    pw_kernel<<<BB*5, 256, 0, stream>>>(qkv_w, proj_w, attn, PW);
    y_kernel<<<BB*128, 256, 0, stream>>>(x, gw, PW, cvec, out);
}

// Round 7
// 254.890 us; speedup vs baseline: 1.1778x; 1.1778x over previous
//
#include <hip/hip_runtime.h>
#include <math.h>

#define BB 16
#define CC 128
#define HH 128
#define WW 128
#define LL 4096

typedef short short8 __attribute__((ext_vector_type(8)));
typedef float f32x4 __attribute__((ext_vector_type(4)));

__device__ __forceinline__ ushort f2bf(float f) {
    union { float f; unsigned u; } un; un.f = f;
    unsigned u = un.u;
    u += 0x7fffu + ((u >> 16) & 1u);   // RNE
    return (ushort)(u >> 16);
}
__device__ __forceinline__ float bf2f(ushort h) {
    union { unsigned u; float f; } un; un.u = ((unsigned)h) << 16;
    return un.f;
}
// tanh-form GELU via sigmoid
__device__ __forceinline__ float fast_gelu(float xv) {
    float x2 = xv*xv;
    float arg = xv*(-2.3022100f - 0.1029436f*x2);
    float e = exp2f(arg);
    return xv*__builtin_amdgcn_rcpf(1.f + e);
}

// ---- prep: Wq/Wk -> bf16; cvec = proj@bv + proj_b ----
__global__ __launch_bounds__(256) void prep_small(
    const float* __restrict__ qkv_w, const float* __restrict__ qkv_b,
    const float* __restrict__ proj_w, const float* __restrict__ proj_b,
    ushort* __restrict__ wqk, float* __restrict__ cvec)
{
    int t = threadIdx.x;
    int gid = blockIdx.x*256 + t;
    wqk[gid] = f2bf(qkv_w[gid]);
    if (blockIdx.x == 1 && t < CC) {
        float s = proj_b[t];
        const float* pr = proj_w + t*CC;
        const float* bv = qkv_b + 2*CC;
        for (int c = 0; c < CC; ++c) s += pr[c]*bv[c];
        cvec[t] = s;
    }
}

// ---- guide = dwconv7x7_s2(gelu(bn(x))), bf16 out [b][c][64*64] ----
// 32x64 output tile; thread = 2v x 4h outputs; LDS row = [4 zero | 128 data | pad]
// stride 144 dwords; chunk-XOR swizzle by (row>>2)&3 -> uniform 8 accesses/bank.
__global__ __launch_bounds__(256) void guide_kernel(
    const float* __restrict__ x, const float* __restrict__ gamma,
    const float* __restrict__ beta, const float* __restrict__ mean,
    const float* __restrict__ var, const float* __restrict__ dww,
    const float* __restrict__ dwb, ushort* __restrict__ gw)
{
    int bc = blockIdx.x;
    int b = bc >> 7, c = bc & 127;
    int ty = blockIdx.y;                      // 0..1: 32 output rows each
    __shared__ __align__(16) float g[69*144]; // 39744 B
    int t = threadIdx.x;
    // uniform weights -> scalar regs
    float wreg[49];
    #pragma unroll
    for (int k = 0; k < 49; ++k) wreg[k] = dww[c*49 + k];
    float bias = dwb[c];
    float scl = gamma[c] * rsqrtf(var[c] + 1e-5f);
    float sft = beta[c] - mean[c]*scl;
    const float* xb = x + (size_t)(b*CC + c)*HH*WW;
    int ihbase = 64*ty - 3;
    // ---- stage: gelu(bn(x)) rows ihbase..ihbase+68, b128 coalesced ----
    #pragma unroll
    for (int k = 0; k < 9; ++k) {
        int idx = k*256 + t;
        if (idx < 69*32) {
            int row = idx >> 5, ch = idx & 31;   // data chunk: cols 4ch..4ch+3
            int ih = ihbase + row;
            float4 v4 = {0.f, 0.f, 0.f, 0.f};
            if ((unsigned)ih < 128u) {
                float4 xv = *(const float4*)(xb + ih*WW + 4*ch);
                v4.x = fast_gelu(xv.x*scl + sft);
                v4.y = fast_gelu(xv.y*scl + sft);
                v4.z = fast_gelu(xv.z*scl + sft);
                v4.w = fast_gelu(xv.w*scl + sft);
            }
            int f = (row >> 2) & 3;
            *(float4*)(g + row*144 + 4*((ch + 1) ^ f)) = v4;   // logical chunk ch+1
        }
    }
    // side zero chunks (logical 0 and 33) per row
    if (t < 138) {
        int row = t >> 1;
        int lc = (t & 1) ? 33 : 0;
        int f = (row >> 2) & 3;
        float4 z4 = {0.f, 0.f, 0.f, 0.f};
        *(float4*)(g + row*144 + 4*(lc ^ f)) = z4;
    }
    __syncthreads();
    // ---- conv: thread (vg,owg) -> out rows {2vg, 2vg+1}, cols 4owg..4owg+3 ----
    int vg = t >> 4, owg = t & 15;
    float acc[2][4];
    #pragma unroll
    for (int v = 0; v < 2; ++v)
        #pragma unroll
        for (int hh = 0; hh < 4; ++hh) acc[v][hh] = bias;
    #pragma unroll
    for (int j = 0; j < 9; ++j) {
        int rr = 4*vg + j;
        int f = (rr >> 2) & 3;
        const float* grow = g + rr*144;
        float win[16];
        #pragma unroll
        for (int i = 0; i < 4; ++i) {
            float4 w4 = *(const float4*)(grow + 4*(((2*owg + i) ^ f)));
            win[4*i+0] = w4.x; win[4*i+1] = w4.y;
            win[4*i+2] = w4.z; win[4*i+3] = w4.w;
        }
        #pragma unroll
        for (int v = 0; v < 2; ++v) {
            int kh = j - 2*v;
            if (kh >= 0 && kh <= 6) {
                #pragma unroll
                for (int hh = 0; hh < 4; ++hh)
                    #pragma unroll
                    for (int kw = 0; kw < 7; ++kw)
                        acc[v][hh] += wreg[kh*7 + kw] * win[2*hh + kw + 1];
            }
        }
    }
    int orbase = 32*ty + 2*vg;
    ushort* gdst = gw + ((size_t)(b*CC + c) << 12);
    #pragma unroll
    for (int v = 0; v < 2; ++v) {
        uint2 pk;
        pk.x = (unsigned)f2bf(acc[v][0]) | ((unsigned)f2bf(acc[v][1]) << 16);
        pk.y = (unsigned)f2bf(acc[v][2]) | ((unsigned)f2bf(acc[v][3]) << 16);
        *(uint2*)(gdst + (orbase + v)*64 + 4*owg) = pk;
    }
}

// ---- stage 5 tokens (bf16) for one 32-l chunk into LDS [m][l][c] pad+8, coalesced ----
__device__ __forceinline__ void stage_tok2(
    ushort* tok, const float* __restrict__ x, const ushort* __restrict__ gw,
    int b, int h, int whalf, int t)
{
    int c = t >> 1, r = t & 1;
    const float* xrow = x + ((size_t)(b*CC + c)*HH + (2*h + r))*WW + whalf*64;
    int m0 = (1 + 2*r)*32, m1 = (2 + 2*r)*32;
    #pragma unroll
    for (int i = 0; i < 16; ++i) {
        float4 v = ((const float4*)xrow)[i];
        tok[(m0 + 2*i    )*136 + c] = f2bf(v.x);
        tok[(m1 + 2*i    )*136 + c] = f2bf(v.y);
        tok[(m0 + 2*i + 1)*136 + c] = f2bf(v.z);
        tok[(m1 + 2*i + 1)*136 + c] = f2bf(v.w);
    }
    const ushort* gsrc = gw + ((size_t)(b*CC + c) << 12) + h*64 + whalf*32 + r*16;
    uint4 g0 = *(const uint4*)gsrc;
    uint4 g1 = *(const uint4*)(gsrc + 8);
    unsigned wd[8] = {g0.x,g0.y,g0.z,g0.w,g1.x,g1.y,g1.z,g1.w};
    #pragma unroll
    for (int k2 = 0; k2 < 8; ++k2) {
        tok[(r*16 + 2*k2    )*136 + c] = (ushort)wd[k2];
        tok[(r*16 + 2*k2 + 1)*136 + c] = (ushort)(wd[k2] >> 16);
    }
}

// ---- phase A: per-block partial S (640) + token-sum partial T (640), 2 chunks/block ----
__global__ __launch_bounds__(256) void s_kernel(
    const float* __restrict__ x, const ushort* __restrict__ gw,
    const ushort* __restrict__ wqk, float* __restrict__ Spart)
{
    __shared__ __align__(16) ushort tok[5*32*136];
    __shared__ float Sred[640];
    int t = threadIdx.x;
    int blk = blockIdx.x;
    int b = blk >> 6, pair = blk & 63;
    int lane = t & 63, wave = t >> 6;
    int strip = wave*32;
    short8 aq[2][4], ak[2][4];
    #pragma unroll
    for (int mt = 0; mt < 2; ++mt)
        #pragma unroll
        for (int kt = 0; kt < 4; ++kt) {
            int off = (strip + mt*16 + (lane & 15))*CC + kt*32 + (lane >> 4)*8;
            aq[mt][kt] = *(const short8*)(wqk + off);
            ak[mt][kt] = *(const short8*)(wqk + CC*CC + off);
        }
    float sacc[5][8];
    #pragma unroll
    for (int m = 0; m < 5; ++m)
        #pragma unroll
        for (int i = 0; i < 8; ++i) sacc[m][i] = 0.f;
    float tacc[3] = {0.f, 0.f, 0.f};
    const ushort* tb = tok + (lane & 15)*136 + (lane >> 4)*8;

    #pragma unroll
    for (int cidx = 0; cidx < 2; ++cidx) {
        int chunk = pair*2 + cidx;
        int h = chunk >> 1, whalf = chunk & 1;
        if (cidx) __syncthreads();
        stage_tok2(tok, x, gw, b, h, whalf, t);
        __syncthreads();
        #pragma unroll
        for (int j = 0; j < 3; ++j) {
            int i = t + j*256;
            if (i < 640) {
                int m = i >> 7, cch = i & 127;
                float s = 0.f;
                for (int l = 0; l < 32; ++l) s += bf2f(tok[(m*32 + l)*136 + cch]);
                tacc[j] += s;
            }
        }
        f32x4 q0[2][2] = {};
        #pragma unroll
        for (int kt = 0; kt < 4; ++kt)
            #pragma unroll
            for (int nt = 0; nt < 2; ++nt) {
                short8 bf = *(const short8*)(tb + (nt*16)*136 + kt*32);
                #pragma unroll
                for (int mt = 0; mt < 2; ++mt)
                    q0[mt][nt] = __builtin_amdgcn_mfma_f32_16x16x32_bf16(aq[mt][kt], bf, q0[mt][nt], 0, 0, 0);
            }
        #pragma unroll
        for (int m = 0; m < 5; ++m) {
            f32x4 ka[2][2] = {};
            #pragma unroll
            for (int kt = 0; kt < 4; ++kt)
                #pragma unroll
                for (int nt = 0; nt < 2; ++nt) {
                    short8 bf = *(const short8*)(tb + (m*32 + nt*16)*136 + kt*32);
                    #pragma unroll
                    for (int mt = 0; mt < 2; ++mt)
                        ka[mt][nt] = __builtin_amdgcn_mfma_f32_16x16x32_bf16(ak[mt][kt], bf, ka[mt][nt], 0, 0, 0);
                }
            #pragma unroll
            for (int mt = 0; mt < 2; ++mt)
                #pragma unroll
                for (int nt = 0; nt < 2; ++nt)
                    #pragma unroll
                    for (int rr = 0; rr < 4; ++rr)
                        sacc[m][mt*4 + rr] += q0[mt][nt][rr]*ka[mt][nt][rr];
        }
    }
    #pragma unroll
    for (int m = 0; m < 5; ++m)
        #pragma unroll
        for (int i = 0; i < 8; ++i) {
            float v = sacc[m][i];
            v += __shfl_xor(v, 1); v += __shfl_xor(v, 2);
            v += __shfl_xor(v, 4); v += __shfl_xor(v, 8);
            if ((lane & 15) == 0)
                Sred[(strip + (i >> 2)*16 + (lane >> 4)*4 + (i & 3))*5 + m] = v;
        }
    __syncthreads();
    float* Sp = Spart + (size_t)blk*1280;
    for (int i = t; i < 640; i += 256) Sp[i] = Sred[i];
    #pragma unroll
    for (int j = 0; j < 3; ++j) {
        int i = t + j*256;
        if (i < 640) Sp[640 + i] = tacc[j];
    }
}

// ---- reduce partials + exact bias + softmax ----
__global__ __launch_bounds__(256) void softmax_attn(
    const float* __restrict__ Spart,
    const float* __restrict__ qkv_w, const float* __restrict__ qkv_b,
    float* __restrict__ attn)
{
    __shared__ float TsumL[640];   // [m][c]
    __shared__ float SL[640];      // [c][m]
    int b = blockIdx.x, t = threadIdx.x;
    for (int i = t; i < 640; i += 256) {
        float s2 = 0.f, ts = 0.f;
        for (int p = 0; p < 64; ++p) {
            const float* row = Spart + (size_t)(b*64 + p)*1280;
            s2 += row[i];
            ts += row[640 + i];
        }
        SL[i] = s2;
        TsumL[i] = ts;
    }
    __syncthreads();
    if (t < CC) {
        int c = t;
        float bq = qkv_b[c], bk = qkv_b[CC + c];
        const float* wqr = qkv_w + c*CC;
        const float* wkr = qkv_w + (CC + c)*CC;
        float t0dot = 0.f;
        for (int j = 0; j < CC; ++j) t0dot += wqr[j]*TsumL[j];
        float s[5];
        #pragma unroll
        for (int m = 0; m < 5; ++m) {
            float km = 0.f;
            for (int j = 0; j < CC; ++j) km += wkr[j]*TsumL[m*128 + j];
            s[m] = SL[c*5 + m] + bq*km + bk*t0dot + (float)LL*bq*bk;
        }
        const float scale = 0.08838834764831845f;  // 1/sqrt(128)
        float mx = s[0]*scale;
        #pragma unroll
        for (int m = 1; m < 5; ++m) mx = fmaxf(mx, s[m]*scale);
        float e[5], tot = 0.f;
        #pragma unroll
        for (int m = 0; m < 5; ++m) { e[m] = expf(s[m]*scale - mx); tot += e[m]; }
        float inv = 1.f/tot;
        #pragma unroll
        for (int m = 0; m < 5; ++m) attn[(b*CC + c)*5 + m] = e[m]*inv;
    }
}

// ---- PW_m[b] = (proj .* attn_m) @ Wv, bf16 [b][m][c_out][c_in] ----
__global__ __launch_bounds__(256) void pw_kernel(
    const float* __restrict__ qkv_w, const float* __restrict__ proj_w,
    const float* __restrict__ attn, ushort* __restrict__ PW)
{
    __shared__ float attns[CC];
    __shared__ float wvs[32*CC];
    int blk = blockIdx.x;
    int b = blk / 5, m = blk % 5;
    int t = threadIdx.x;
    if (t < CC) attns[t] = attn[(b*CC + t)*5 + m];
    int d = t >> 1, cb = (t & 1)*64;
    float acc[64];
    #pragma unroll
    for (int j = 0; j < 64; ++j) acc[j] = 0.f;
    for (int cc0 = 0; cc0 < CC; cc0 += 32) {
        __syncthreads();
        for (int idx = t; idx < 32*CC; idx += 256) {
            int row = idx >> 7, col = idx & 127;
            wvs[idx] = qkv_w[(2*CC + cc0 + row)*CC + col];
        }
        __syncthreads();
        for (int cl = 0; cl < 32; ++cl) {
            int c = cc0 + cl;
            float a = proj_w[d*CC + c]*attns[c];
            const float* wr = wvs + cl*CC + cb;
            #pragma unroll
            for (int j = 0; j < 64; ++j) acc[j] += a*wr[j];
        }
    }
    ushort* dst = PW + ((size_t)(b*5 + m) << 14) + d*CC + cb;
    #pragma unroll
    for (int j = 0; j < 64; ++j) dst[j] = f2bf(acc[j]);
}

// ---- phase B: Y[l][c_out] = sum_{m,c} tok[m][l][c] * PW_m[c_out][c] + cvec ----
__global__ __launch_bounds__(256) void y_kernel(
    const float* __restrict__ x, const ushort* __restrict__ gw,
    const ushort* __restrict__ PW, const float* __restrict__ cvec,
    float* __restrict__ out)
{
    __shared__ __align__(16) ushort tok[5*32*136];   // reused as ylds[128][36] f32
    int t = threadIdx.x;
    int b = blockIdx.x >> 7, chunk = blockIdx.x & 127;
    int h = chunk >> 1, whalf = chunk & 1;
    stage_tok2(tok, x, gw, b, h, whalf, t);
    __syncthreads();
    int lane = t & 63, wave = t >> 6;
    const ushort* ta = tok + (lane & 15)*136 + (lane >> 4)*8;  // A: row=l, k=c
    f32x4 acc[2][2] = {};
    #pragma unroll
    for (int m = 0; m < 5; ++m) {
        const ushort* pwb = PW + ((size_t)(b*5 + m) << 14)
                          + ((wave*32 + (lane & 15)) << 7) + ((lane >> 4) << 3);
        #pragma unroll
        for (int kt = 0; kt < 4; ++kt) {
            short8 a0 = *(const short8*)(ta + (m*32     )*136 + kt*32);
            short8 a1 = *(const short8*)(ta + (m*32 + 16)*136 + kt*32);
            short8 b0 = *(const short8*)(pwb + kt*32);
            short8 b1 = *(const short8*)(pwb + (16 << 7) + kt*32);
            acc[0][0] = __builtin_amdgcn_mfma_f32_16x16x32_bf16(a0, b0, acc[0][0], 0, 0, 0);
            acc[0][1] = __builtin_amdgcn_mfma_f32_16x16x32_bf16(a0, b1, acc[0][1], 0, 0, 0);
            acc[1][0] = __builtin_amdgcn_mfma_f32_16x16x32_bf16(a1, b0, acc[1][0], 0, 0, 0);
            acc[1][1] = __builtin_amdgcn_mfma_f32_16x16x32_bf16(a1, b1, acc[1][1], 0, 0, 0);
        }
    }
    __syncthreads();
    float* ylds = (float*)tok;   // [128][36]
    #pragma unroll
    for (int mt = 0; mt < 2; ++mt)
        #pragma unroll
        for (int ntl = 0; ntl < 2; ++ntl) {
            int cc = wave*32 + ntl*16 + (lane & 15);
            float cv = cvec[cc];
            #pragma unroll
            for (int rr = 0; rr < 4; ++rr) {
                int l = mt*16 + (lane >> 4)*4 + rr;
                ylds[cc*36 + l] = acc[mt][ntl][rr] + cv;
            }
        }
    __syncthreads();
    int c = t >> 1, half = t & 1;
    float* ob = out + ((size_t)(b*CC + c) << 12) + h*64 + whalf*32 + half*16;
    const float* yr = ylds + c*36 + half*16;
    #pragma unroll
    for (int j = 0; j < 4; ++j)
        ((float4*)ob)[j] = ((const float4*)yr)[j];
}

extern "C" void kernel_launch(void* const* d_in, const int* in_sizes, int n_in,
                              void* d_out, int out_size, void* d_ws, size_t ws_size,
                              hipStream_t stream) {
    const float* x        = (const float*)d_in[0];
    const float* bn_gamma = (const float*)d_in[1];
    const float* bn_beta  = (const float*)d_in[2];
    const float* bn_mean  = (const float*)d_in[3];
    const float* bn_var   = (const float*)d_in[4];
    const float* dw_w     = (const float*)d_in[5];
    const float* dw_b     = (const float*)d_in[6];
    const float* qkv_w    = (const float*)d_in[7];
    const float* qkv_b    = (const float*)d_in[8];
    const float* proj_w   = (const float*)d_in[9];
    const float* proj_b   = (const float*)d_in[10];
    float* out = (float*)d_out;

    char* w = (char*)d_ws;
    ushort* gw    = (ushort*)w; w += (size_t)BB*CC*LL*2;        // 16 MB
    ushort* wqk   = (ushort*)w; w += (size_t)2*CC*CC*2;         // 64 KB
    ushort* PW    = (ushort*)w; w += (size_t)BB*5*CC*CC*2;      // 2.5 MB
    float*  Spart = (float*)w;  w += (size_t)1024*1280*4;       // 5.24 MB
    float*  attn  = (float*)w;  w += (size_t)BB*CC*5*4;         // 40 KB
    float*  cvec  = (float*)w;  w += (size_t)CC*4;

    prep_small<<<128, 256, 0, stream>>>(qkv_w, qkv_b, proj_w, proj_b, wqk, cvec);
    guide_kernel<<<dim3(BB*CC, 2), 256, 0, stream>>>(
        x, bn_gamma, bn_beta, bn_mean, bn_var, dw_w, dw_b, gw);
    s_kernel<<<1024, 256, 0, stream>>>(x, gw, wqk, Spart);
    softmax_attn<<<BB, 256, 0, stream>>>(Spart, qkv_w, qkv_b, attn);
    pw_kernel<<<BB*5, 256, 0, stream>>>(qkv_w, proj_w, attn, PW);
    y_kernel<<<BB*128, 256, 0, stream>>>(x, gw, PW, cvec, out);
}